// Round 1
// baseline (579.906 us; speedup 1.0000x reference)
//
#include <hip/hip_runtime.h>
#include <math.h>

#define TILE 32
#define HALO 42  // TILE + 10

// ---------------------------------------------------------------------------
// init: compute 11-tap Gaussian in double (matches numpy f64 -> f32 cast),
// zero the 10 double accumulators (ws is poisoned 0xAA before every call).
// ---------------------------------------------------------------------------
__global__ void msssim_init_kernel(double* __restrict__ accum, float* __restrict__ g) {
    if (threadIdx.x == 0) {
        double w[11]; double s = 0.0;
        for (int i = 0; i < 11; ++i) { double x = (double)(i - 5); w[i] = exp(-(x * x) / 4.5); s += w[i]; }
        for (int i = 0; i < 11; ++i) g[i] = (float)(w[i] / s);
        for (int i = 0; i < 10; ++i) accum[i] = 0.0;
    }
}

// ---------------------------------------------------------------------------
// Per-level SSIM: separable 11x11 Gaussian conv of {x, y, x^2, y^2, xy},
// SSIM-map + CS-map values, block reduction, double atomic accumulate.
// Grid: (ceil(Wv/TILE), ceil(Hv/TILE), N*C). Block: 256 threads.
// ---------------------------------------------------------------------------
__global__ __launch_bounds__(256) void ssim_level_kernel(
    const float* __restrict__ img1, const float* __restrict__ img2,
    int H, int W, const float* __restrict__ gg,
    double* __restrict__ accum, int level)
{
    __shared__ float s1[HALO][HALO + 2];
    __shared__ float s2[HALO][HALO + 2];
    __shared__ float sh[5][HALO][TILE];
    __shared__ float g[11];
    __shared__ float red[8];

    const int tid = threadIdx.x;
    if (tid < 11) g[tid] = gg[tid];

    const int Hv = H - 10, Wv = W - 10;
    const int bx = blockIdx.x * TILE, by = blockIdx.y * TILE;
    const size_t plane = (size_t)blockIdx.z * (size_t)H * (size_t)W;
    const float* __restrict__ p1 = img1 + plane;
    const float* __restrict__ p2 = img2 + plane;

    // ---- stage halo tile (zero-pad out of range; those outputs are skipped)
    for (int i = tid; i < HALO * HALO; i += 256) {
        int r = i / HALO, c = i - r * HALO;
        int y = by + r, x = bx + c;
        float a = 0.f, b = 0.f;
        if (y < H && x < W) {
            size_t o = (size_t)y * W + x;
            a = p1[o]; b = p2[o];
        }
        s1[r][c] = a; s2[r][c] = b;
    }
    __syncthreads();

    // ---- horizontal separable pass over 5 quantities
    for (int i = tid; i < HALO * TILE; i += 256) {
        int r = i / TILE, c = i - r * TILE;
        float m1 = 0.f, m2 = 0.f, q11 = 0.f, q22 = 0.f, q12 = 0.f;
#pragma unroll
        for (int k = 0; k < 11; ++k) {
            float wk = g[k];
            float a = s1[r][c + k], b = s2[r][c + k];
            m1  += a * wk;
            m2  += b * wk;
            q11 += a * a * wk;
            q22 += b * b * wk;
            q12 += a * b * wk;
        }
        sh[0][r][c] = m1; sh[1][r][c] = m2;
        sh[2][r][c] = q11; sh[3][r][c] = q22; sh[4][r][c] = q12;
    }
    __syncthreads();

    // ---- vertical pass + SSIM formula + local accumulate
    const float C1 = 0.0004f;   // (0.01*2)^2
    const float C2 = 0.0036f;   // (0.03*2)^2
    float ssim_local = 0.f, cs_local = 0.f;
    for (int i = tid; i < TILE * TILE; i += 256) {
        int ty = i >> 5, tx = i & 31;
        int oy = by + ty, ox = bx + tx;
        if (oy < Hv && ox < Wv) {
            float mu1 = 0.f, mu2 = 0.f, x11 = 0.f, x22 = 0.f, x12 = 0.f;
#pragma unroll
            for (int k = 0; k < 11; ++k) {
                float wk = g[k];
                mu1 += sh[0][ty + k][tx] * wk;
                mu2 += sh[1][ty + k][tx] * wk;
                x11 += sh[2][ty + k][tx] * wk;
                x22 += sh[3][ty + k][tx] * wk;
                x12 += sh[4][ty + k][tx] * wk;
            }
            float mu1sq = mu1 * mu1, mu2sq = mu2 * mu2, mu12 = mu1 * mu2;
            float sig1 = x11 - mu1sq, sig2 = x22 - mu2sq, sig12 = x12 - mu12;
            float v1 = 2.f * sig12 + C2;
            float v2 = sig1 + sig2 + C2;
            cs_local += v1 / v2;
            ssim_local += ((2.f * mu12 + C1) * v1) / ((mu1sq + mu2sq + C1) * v2);
        }
    }

    // ---- block reduction (4 waves of 64)
#pragma unroll
    for (int off = 32; off > 0; off >>= 1) {
        ssim_local += __shfl_down(ssim_local, off);
        cs_local   += __shfl_down(cs_local, off);
    }
    int wave = tid >> 6, lane = tid & 63;
    if (lane == 0) { red[wave] = ssim_local; red[4 + wave] = cs_local; }
    __syncthreads();
    if (tid == 0) {
        float ss = red[0] + red[1] + red[2] + red[3];
        float cc = red[4] + red[5] + red[6] + red[7];
        atomicAdd(&accum[level], (double)ss);
        atomicAdd(&accum[5 + level], (double)cc);
    }
}

// ---------------------------------------------------------------------------
// 2x2 average pool for both images.
// ---------------------------------------------------------------------------
__global__ __launch_bounds__(256) void downsample_kernel(
    const float* __restrict__ in1, const float* __restrict__ in2,
    float* __restrict__ out1, float* __restrict__ out2,
    int Hout, int Wout, long long total)
{
    long long idx = (long long)blockIdx.x * 256 + threadIdx.x;
    if (idx >= total) return;
    int x = (int)(idx % Wout);
    long long t = idx / Wout;
    int y = (int)(t % Hout);
    int nc = (int)(t / Hout);
    size_t Win = (size_t)(2 * Wout);
    size_t rowbase = ((size_t)nc * (2 * Hout) + (size_t)(2 * y)) * Win + (size_t)(2 * x);
    float2 a0 = *(const float2*)(in1 + rowbase);
    float2 a1 = *(const float2*)(in1 + rowbase + Win);
    out1[idx] = (a0.x + a0.y + a1.x + a1.y) * 0.25f;
    float2 b0 = *(const float2*)(in2 + rowbase);
    float2 b1 = *(const float2*)(in2 + rowbase + Win);
    out2[idx] = (b0.x + b0.y + b1.x + b1.y) * 0.25f;
}

// ---------------------------------------------------------------------------
// Final scalar: loss = 1 - cs4^w4 * prod_i ssim_i^w_i   (all in double)
// ---------------------------------------------------------------------------
__global__ void msssim_final_kernel(const double* __restrict__ accum, float* __restrict__ out) {
    if (threadIdx.x == 0 && blockIdx.x == 0) {
        const double counts[5] = {
            48.0 * 502.0 * 502.0,
            48.0 * 246.0 * 246.0,
            48.0 * 118.0 * 118.0,
            48.0 * 54.0 * 54.0,
            48.0 * 22.0 * 22.0
        };
        const double w[5] = { (double)0.0448f, (double)0.2856f, (double)0.3001f,
                              (double)0.2363f, (double)0.1333f };
        double prod = 1.0;
        for (int i = 0; i < 5; ++i) prod *= pow(accum[i] / counts[i], w[i]);
        double mcs = accum[9] / counts[4];   // cs of LAST level
        double output = pow(mcs, w[4]) * prod;
        out[0] = (float)(1.0 - output);
    }
}

// ---------------------------------------------------------------------------
extern "C" void kernel_launch(void* const* d_in, const int* in_sizes, int n_in,
                              void* d_out, int out_size, void* d_ws, size_t ws_size,
                              hipStream_t stream) {
    const float* img1 = (const float*)d_in[0];
    const float* img2 = (const float*)d_in[1];
    float* out = (float*)d_out;

    char* ws = (char*)d_ws;
    double* accum = (double*)ws;            // 10 doubles (80 B)
    float* g = (float*)(ws + 128);          // 11 floats
    float* buf = (float*)(ws + 256);        // pyramid buffers

    const int NC = 48;                      // 16 * 3
    const int Hs[5] = {512, 256, 128, 64, 32};

    const float* A[5]; const float* B[5];
    A[0] = img1; B[0] = img2;
    size_t o = 0;
    float* Aw[5]; float* Bw[5];
    for (int l = 1; l < 5; ++l) {
        size_t n = (size_t)NC * Hs[l] * Hs[l];
        Aw[l] = buf + o; o += n;
        Bw[l] = buf + o; o += n;
        A[l] = Aw[l]; B[l] = Bw[l];
    }

    msssim_init_kernel<<<dim3(1), dim3(64), 0, stream>>>(accum, g);

    for (int l = 0; l < 5; ++l) {
        int H = Hs[l];
        int Hv = H - 10;
        int nt = (Hv + TILE - 1) / TILE;
        dim3 grid(nt, nt, NC);
        ssim_level_kernel<<<grid, dim3(256), 0, stream>>>(A[l], B[l], H, H, g, accum, l);
        if (l < 4) {
            int Ho = H / 2;
            long long total = (long long)NC * Ho * Ho;
            int blocks = (int)((total + 255) / 256);
            downsample_kernel<<<dim3(blocks), dim3(256), 0, stream>>>(
                A[l], B[l], (float*)A[l + 1], (float*)B[l + 1], Ho, Ho, total);
        }
    }

    msssim_final_kernel<<<dim3(1), dim3(64), 0, stream>>>(accum, out);
}

// Round 2
// 523.349 us; speedup vs baseline: 1.1081x; 1.1081x over previous
//
#include <hip/hip_runtime.h>
#include <math.h>

#define TS 32      // output tile (TS x TS)
#define HW 42      // halo width = TS + 10
#define SPAD 44    // sAB column stride (float2 pairs) -> 352 B rows, 16B-aligned
#define VPAD 45    // vrt column stride (float4)       -> odd S/4 spreads banks

// ---------------------------------------------------------------------------
// init: 11-tap Gaussian in double (matches numpy f64 -> f32 cast), zero accums.
// ---------------------------------------------------------------------------
__global__ void msssim_init_kernel(double* __restrict__ accum, float* __restrict__ g) {
    if (threadIdx.x == 0) {
        double w[11]; double s = 0.0;
        for (int i = 0; i < 11; ++i) { double x = (double)(i - 5); w[i] = exp(-(x * x) / 4.5); s += w[i]; }
        for (int i = 0; i < 11; ++i) g[i] = (float)(w[i] / s);
        for (int i = 0; i < 10; ++i) accum[i] = 0.0;
    }
}

// products per pixel: {a, b, a^2+b^2, a*b}
__device__ __forceinline__ float4 prodf(float2 ab) {
    return make_float4(ab.x, ab.y, fmaf(ab.x, ab.x, ab.y * ab.y), ab.x * ab.y);
}

// 11-tap conv over rotating window w[(I+k)%11], all indices compile-time.
template<int I>
__device__ __forceinline__ float4 conv11(const float4 (&w)[11], const float (&g)[11]) {
    const float4& w0 = w[I % 11];
    float4 r;
    r.x = w0.x * g[0]; r.y = w0.y * g[0]; r.z = w0.z * g[0]; r.w = w0.w * g[0];
#pragma unroll
    for (int k = 1; k < 11; ++k) {
        const float4& wk = w[(I + k) % 11];
        r.x = fmaf(g[k], wk.x, r.x);
        r.y = fmaf(g[k], wk.y, r.y);
        r.z = fmaf(g[k], wk.z, r.z);
        r.w = fmaf(g[k], wk.w, r.w);
    }
    return r;
}

// ---------------------------------------------------------------------------
// Fused per-level kernel: stage tile -> (2x2 avg-pool to next level) ->
// vertical 11-tap conv (register sliding window) -> horizontal 11-tap conv
// (register sliding window) + SSIM/CS formula -> block reduce -> f64 atomics.
// Grid: (H/32, H/32, 48). Block: 256.
// ---------------------------------------------------------------------------
__global__ __launch_bounds__(256, 4) void ssim_fused_kernel(
    const float* __restrict__ img1, const float* __restrict__ img2,
    int H, const float* __restrict__ gg,
    double* __restrict__ accum, int level,
    float* __restrict__ o1, float* __restrict__ o2)
{
    __shared__ __align__(16) float2 sAB[HW][SPAD];  // {a,b} interleaved, 14784 B
    __shared__ __align__(16) float4 vrt[TS][VPAD];  // {mu1,mu2,ss,s12}, 23040 B
    __shared__ float gsh[11];
    __shared__ float red[8];

    const int tid = threadIdx.x;
    if (tid < 11) gsh[tid] = gg[tid];

    const int W = H, Hv = H - 10, Wv = W - 10;
    const int bx = blockIdx.x * TS, by = blockIdx.y * TS;
    const size_t plane = (size_t)blockIdx.z * (size_t)H * (size_t)W;
    const float* __restrict__ p1 = img1 + plane;
    const float* __restrict__ p2 = img2 + plane;

    // ---- stage halo tile: pairs of pixels, write {a0,b0,a1,b1} as b128
    for (int i = tid; i < HW * 21; i += 256) {
        int r = i / 21, j = i - r * 21, cc = 2 * j;
        int y = by + r, x = bx + cc;
        float2 a = make_float2(0.f, 0.f), b = a;
        if (y < H && x + 1 < W) {
            size_t o = (size_t)y * W + x;
            a = *(const float2*)(p1 + o);
            b = *(const float2*)(p2 + o);
        }
        *(float4*)&sAB[r][cc] = make_float4(a.x, b.x, a.y, b.y);
    }
    __syncthreads();

    float g[11];
#pragma unroll
    for (int j = 0; j < 11; ++j) g[j] = gsh[j];

    // ---- fused 2x2 avg-pool of this block's owned 32x32 input region
    if (o1) {
        int py = tid >> 4, px = tid & 15;
        float4 q0 = *(const float4*)&sAB[2 * py][2 * px];
        float4 q1 = *(const float4*)&sAB[2 * py + 1][2 * px];
        int Hp = H >> 1;
        size_t po = (size_t)blockIdx.z * Hp * Hp + (size_t)((by >> 1) + py) * Hp + (bx >> 1) + px;
        o1[po] = 0.25f * ((q0.x + q0.z) + (q1.x + q1.z));
        o2[po] = 0.25f * ((q0.y + q0.w) + (q1.y + q1.w));
    }

    // ---- vertical conv: 42 cols x 6 row-chunks (rows 6,6,5,5,5,5)
    if (tid < 252) {
        int c = tid % 42, ch = tid / 42;
        int r0 = 6 * ch - max(0, ch - 2);          // {0,6,12,17,22,27}
        int len = (ch >= 2) ? 5 : 6;
        float4 w[11];
#pragma unroll
        for (int j = 0; j < 10; ++j) w[j] = prodf(sAB[r0 + j][c]);
#define P1STEP(I)                                                      \
        if ((I) < 5 || len == 6) {                                     \
            w[(10 + (I)) % 11] = prodf(sAB[r0 + 10 + (I)][c]);         \
            vrt[r0 + (I)][c] = conv11<(I)>(w, g);                      \
        }
        P1STEP(0) P1STEP(1) P1STEP(2) P1STEP(3) P1STEP(4) P1STEP(5)
#undef P1STEP
    }
    __syncthreads();

    // ---- horizontal conv + SSIM formula: 32 rows x 8 threads x 4 cols each
    const float C1 = 0.0004f;   // (0.01*2)^2
    const float C2 = 0.0036f;   // (0.03*2)^2
    float ssim_l = 0.f, cs_l = 0.f;
    {
        int row = tid >> 3, s = tid & 7, c0 = s * 4;
        int oy = by + row;
        float4 w[11];
#pragma unroll
        for (int j = 0; j < 10; ++j) w[j] = vrt[row][c0 + j];
#define P2STEP(I)                                                      \
        {                                                              \
            w[(10 + (I)) % 11] = vrt[row][c0 + 10 + (I)];              \
            float4 m = conv11<(I)>(w, g);                              \
            int ox = bx + c0 + (I);                                    \
            if (oy < Hv && ox < Wv) {                                  \
                float ab   = m.x * m.y;                                \
                float aabb = fmaf(m.x, m.x, m.y * m.y);                \
                float n1   = fmaf(2.f, ab, C1);                        \
                float d1   = aabb + C1;                                \
                float v1   = fmaf(2.f, m.w - ab, C2);                  \
                float v2   = (m.z - aabb) + C2;                        \
                float rden = 1.f / (d1 * v2);                          \
                cs_l   = fmaf(v1 * d1, rden, cs_l);                    \
                ssim_l = fmaf(n1 * v1, rden, ssim_l);                  \
            }                                                          \
        }
        P2STEP(0) P2STEP(1) P2STEP(2) P2STEP(3)
#undef P2STEP
    }

    // ---- block reduction (4 waves of 64) + double atomics
#pragma unroll
    for (int off = 32; off > 0; off >>= 1) {
        ssim_l += __shfl_down(ssim_l, off);
        cs_l   += __shfl_down(cs_l, off);
    }
    int wave = tid >> 6, lane = tid & 63;
    if (lane == 0) { red[wave] = ssim_l; red[4 + wave] = cs_l; }
    __syncthreads();
    if (tid == 0) {
        float ss = red[0] + red[1] + red[2] + red[3];
        float cc = red[4] + red[5] + red[6] + red[7];
        atomicAdd(&accum[level], (double)ss);
        atomicAdd(&accum[5 + level], (double)cc);
    }
}

// ---------------------------------------------------------------------------
// Final scalar: loss = 1 - cs4^w4 * prod_i ssim_i^w_i   (all in double)
// ---------------------------------------------------------------------------
__global__ void msssim_final_kernel(const double* __restrict__ accum, float* __restrict__ out) {
    if (threadIdx.x == 0 && blockIdx.x == 0) {
        const double counts[5] = {
            48.0 * 502.0 * 502.0,
            48.0 * 246.0 * 246.0,
            48.0 * 118.0 * 118.0,
            48.0 * 54.0 * 54.0,
            48.0 * 22.0 * 22.0
        };
        const double w[5] = { (double)0.0448f, (double)0.2856f, (double)0.3001f,
                              (double)0.2363f, (double)0.1333f };
        double prod = 1.0;
        for (int i = 0; i < 5; ++i) prod *= pow(accum[i] / counts[i], w[i]);
        double mcs = accum[9] / counts[4];   // cs of LAST level
        double output = pow(mcs, w[4]) * prod;
        out[0] = (float)(1.0 - output);
    }
}

// ---------------------------------------------------------------------------
extern "C" void kernel_launch(void* const* d_in, const int* in_sizes, int n_in,
                              void* d_out, int out_size, void* d_ws, size_t ws_size,
                              hipStream_t stream) {
    const float* img1 = (const float*)d_in[0];
    const float* img2 = (const float*)d_in[1];
    float* out = (float*)d_out;

    char* ws = (char*)d_ws;
    double* accum = (double*)ws;            // 10 doubles
    float* g = (float*)(ws + 128);          // 11 floats
    float* buf = (float*)(ws + 256);        // pyramid buffers

    const int NC = 48;                      // 16 * 3
    const int Hs[5] = {512, 256, 128, 64, 32};

    const float* A[5]; const float* B[5];
    float* Aw[5]; float* Bw[5];
    A[0] = img1; B[0] = img2;
    Aw[0] = Bw[0] = nullptr;
    size_t o = 0;
    for (int l = 1; l < 5; ++l) {
        size_t n = (size_t)NC * Hs[l] * Hs[l];
        Aw[l] = buf + o; o += n;
        Bw[l] = buf + o; o += n;
        A[l] = Aw[l]; B[l] = Bw[l];
    }

    msssim_init_kernel<<<dim3(1), dim3(64), 0, stream>>>(accum, g);

    for (int l = 0; l < 5; ++l) {
        int H = Hs[l];
        int nt = H / TS;                    // exact for all 5 levels
        dim3 grid(nt, nt, NC);
        float* po1 = (l < 4) ? Aw[l + 1] : nullptr;
        float* po2 = (l < 4) ? Bw[l + 1] : nullptr;
        ssim_fused_kernel<<<grid, dim3(256), 0, stream>>>(
            A[l], B[l], H, g, accum, l, po1, po2);
    }

    msssim_final_kernel<<<dim3(1), dim3(64), 0, stream>>>(accum, out);
}

// Round 3
// 228.634 us; speedup vs baseline: 2.5364x; 2.2890x over previous
//
#include <hip/hip_runtime.h>
#include <math.h>

#define TS 32      // output tile (TS x TS)
#define HW 42      // halo width = TS + 10
#define SPAD 44    // sAB column stride (float2 pairs) -> 352 B rows, 16B-aligned
#define VPAD 45    // vrt column stride (float4)       -> odd S/4 spreads banks

// per-level block counts / offsets into the partials buffer (grid = (H/32)^2 * 48)
#define NB0 12288
#define NB1 3072
#define NB2 768
#define NB3 192
#define NB4 48
#define NPART 16368

// ---------------------------------------------------------------------------
// init: 11-tap Gaussian in double (matches numpy f64 -> f32 cast).
// ---------------------------------------------------------------------------
__global__ void msssim_init_kernel(float* __restrict__ g) {
    if (threadIdx.x == 0) {
        double w[11]; double s = 0.0;
        for (int i = 0; i < 11; ++i) { double x = (double)(i - 5); w[i] = exp(-(x * x) / 4.5); s += w[i]; }
        for (int i = 0; i < 11; ++i) g[i] = (float)(w[i] / s);
    }
}

// products per pixel: {a, b, a^2+b^2, a*b}
__device__ __forceinline__ float4 prodf(float2 ab) {
    return make_float4(ab.x, ab.y, fmaf(ab.x, ab.x, ab.y * ab.y), ab.x * ab.y);
}

// 11-tap conv over rotating window w[(I+k)%11], all indices compile-time.
template<int I>
__device__ __forceinline__ float4 conv11(const float4 (&w)[11], const float (&g)[11]) {
    const float4& w0 = w[I % 11];
    float4 r;
    r.x = w0.x * g[0]; r.y = w0.y * g[0]; r.z = w0.z * g[0]; r.w = w0.w * g[0];
#pragma unroll
    for (int k = 1; k < 11; ++k) {
        const float4& wk = w[(I + k) % 11];
        r.x = fmaf(g[k], wk.x, r.x);
        r.y = fmaf(g[k], wk.y, r.y);
        r.z = fmaf(g[k], wk.z, r.z);
        r.w = fmaf(g[k], wk.w, r.w);
    }
    return r;
}

// ---------------------------------------------------------------------------
// Fused per-level kernel: stage tile -> (2x2 avg-pool to next level) ->
// vertical 11-tap conv (register sliding window) -> horizontal 11-tap conv
// (register sliding window) + SSIM/CS formula -> block reduce ->
// per-block float2 partial store (NO contended atomics).
// Grid: (H/32, H/32, 48). Block: 256.
// ---------------------------------------------------------------------------
__global__ __launch_bounds__(256, 4) void ssim_fused_kernel(
    const float* __restrict__ img1, const float* __restrict__ img2,
    int H, const float* __restrict__ gg,
    float2* __restrict__ partials,
    float* __restrict__ o1, float* __restrict__ o2)
{
    __shared__ __align__(16) float2 sAB[HW][SPAD];  // {a,b} interleaved, 14784 B
    __shared__ __align__(16) float4 vrt[TS][VPAD];  // {mu1,mu2,ss,s12}, 23040 B
    __shared__ float gsh[11];
    __shared__ float red[8];

    const int tid = threadIdx.x;
    if (tid < 11) gsh[tid] = gg[tid];

    const int W = H, Hv = H - 10, Wv = W - 10;
    const int bx = blockIdx.x * TS, by = blockIdx.y * TS;
    const size_t plane = (size_t)blockIdx.z * (size_t)H * (size_t)W;
    const float* __restrict__ p1 = img1 + plane;
    const float* __restrict__ p2 = img2 + plane;

    // ---- stage halo tile: pairs of pixels, write {a0,b0,a1,b1} as b128
    for (int i = tid; i < HW * 21; i += 256) {
        int r = i / 21, j = i - r * 21, cc = 2 * j;
        int y = by + r, x = bx + cc;
        float2 a = make_float2(0.f, 0.f), b = a;
        if (y < H && x + 1 < W) {
            size_t o = (size_t)y * W + x;
            a = *(const float2*)(p1 + o);
            b = *(const float2*)(p2 + o);
        }
        *(float4*)&sAB[r][cc] = make_float4(a.x, b.x, a.y, b.y);
    }
    __syncthreads();

    float g[11];
#pragma unroll
    for (int j = 0; j < 11; ++j) g[j] = gsh[j];

    // ---- fused 2x2 avg-pool of this block's owned 32x32 input region
    if (o1) {
        int py = tid >> 4, px = tid & 15;
        float4 q0 = *(const float4*)&sAB[2 * py][2 * px];
        float4 q1 = *(const float4*)&sAB[2 * py + 1][2 * px];
        int Hp = H >> 1;
        size_t po = (size_t)blockIdx.z * Hp * Hp + (size_t)((by >> 1) + py) * Hp + (bx >> 1) + px;
        o1[po] = 0.25f * ((q0.x + q0.z) + (q1.x + q1.z));
        o2[po] = 0.25f * ((q0.y + q0.w) + (q1.y + q1.w));
    }

    // ---- vertical conv: 42 cols x 6 row-chunks (rows 6,6,5,5,5,5)
    if (tid < 252) {
        int c = tid % 42, ch = tid / 42;
        int r0 = 6 * ch - max(0, ch - 2);          // {0,6,12,17,22,27}
        int len = (ch >= 2) ? 5 : 6;
        float4 w[11];
#pragma unroll
        for (int j = 0; j < 10; ++j) w[j] = prodf(sAB[r0 + j][c]);
#define P1STEP(I)                                                      \
        if ((I) < 5 || len == 6) {                                     \
            w[(10 + (I)) % 11] = prodf(sAB[r0 + 10 + (I)][c]);         \
            vrt[r0 + (I)][c] = conv11<(I)>(w, g);                      \
        }
        P1STEP(0) P1STEP(1) P1STEP(2) P1STEP(3) P1STEP(4) P1STEP(5)
#undef P1STEP
    }
    __syncthreads();

    // ---- horizontal conv + SSIM formula: 32 rows x 8 threads x 4 cols each
    const float C1 = 0.0004f;   // (0.01*2)^2
    const float C2 = 0.0036f;   // (0.03*2)^2
    float ssim_l = 0.f, cs_l = 0.f;
    {
        int row = tid >> 3, s = tid & 7, c0 = s * 4;
        int oy = by + row;
        float4 w[11];
#pragma unroll
        for (int j = 0; j < 10; ++j) w[j] = vrt[row][c0 + j];
#define P2STEP(I)                                                      \
        {                                                              \
            w[(10 + (I)) % 11] = vrt[row][c0 + 10 + (I)];              \
            float4 m = conv11<(I)>(w, g);                              \
            int ox = bx + c0 + (I);                                    \
            if (oy < Hv && ox < Wv) {                                  \
                float ab   = m.x * m.y;                                \
                float aabb = fmaf(m.x, m.x, m.y * m.y);                \
                float n1   = fmaf(2.f, ab, C1);                        \
                float d1   = aabb + C1;                                \
                float v1   = fmaf(2.f, m.w - ab, C2);                  \
                float v2   = (m.z - aabb) + C2;                        \
                float rden = 1.f / (d1 * v2);                          \
                cs_l   = fmaf(v1 * d1, rden, cs_l);                    \
                ssim_l = fmaf(n1 * v1, rden, ssim_l);                  \
            }                                                          \
        }
        P2STEP(0) P2STEP(1) P2STEP(2) P2STEP(3)
#undef P2STEP
    }

    // ---- block reduction (4 waves of 64) -> one float2 store per block
#pragma unroll
    for (int off = 32; off > 0; off >>= 1) {
        ssim_l += __shfl_down(ssim_l, off);
        cs_l   += __shfl_down(cs_l, off);
    }
    int wave = tid >> 6, lane = tid & 63;
    if (lane == 0) { red[wave] = ssim_l; red[4 + wave] = cs_l; }
    __syncthreads();
    if (tid == 0) {
        float ss = red[0] + red[1] + red[2] + red[3];
        float cc = red[4] + red[5] + red[6] + red[7];
        int nt = gridDim.x;
        int bid = ((int)blockIdx.z * nt + (int)blockIdx.y) * nt + (int)blockIdx.x;
        partials[bid] = make_float2(ss, cc);
    }
}

// ---------------------------------------------------------------------------
// Final reduce: sum per-level partials in double, then
// loss = 1 - cs4^w4 * prod_i ssim_i^w_i   (all in double). One block, 1024 thr.
// ---------------------------------------------------------------------------
__global__ __launch_bounds__(1024) void msssim_reduce_kernel(
    const float2* __restrict__ partials, float* __restrict__ out)
{
    __shared__ double sred[16][2];
    __shared__ double lev[10];
    const int NB[5]  = {NB0, NB1, NB2, NB3, NB4};
    const int OFF[5] = {0, NB0, NB0 + NB1, NB0 + NB1 + NB2, NB0 + NB1 + NB2 + NB3};
    const int tid = threadIdx.x;
    const int wv = tid >> 6, ln = tid & 63;

    for (int l = 0; l < 5; ++l) {
        double s = 0.0, c = 0.0;
        for (int i = tid; i < NB[l]; i += 1024) {
            float2 p = partials[OFF[l] + i];
            s += (double)p.x; c += (double)p.y;
        }
#pragma unroll
        for (int off = 32; off > 0; off >>= 1) {
            s += __shfl_down(s, off);
            c += __shfl_down(c, off);
        }
        if (ln == 0) { sred[wv][0] = s; sred[wv][1] = c; }
        __syncthreads();
        if (tid == 0) {
            double ss = 0.0, cc = 0.0;
            for (int w = 0; w < 16; ++w) { ss += sred[w][0]; cc += sred[w][1]; }
            lev[l] = ss; lev[5 + l] = cc;
        }
        __syncthreads();
    }

    if (tid == 0) {
        const double counts[5] = {
            48.0 * 502.0 * 502.0,
            48.0 * 246.0 * 246.0,
            48.0 * 118.0 * 118.0,
            48.0 * 54.0 * 54.0,
            48.0 * 22.0 * 22.0
        };
        const double w[5] = { (double)0.0448f, (double)0.2856f, (double)0.3001f,
                              (double)0.2363f, (double)0.1333f };
        double prod = 1.0;
        for (int i = 0; i < 5; ++i) prod *= pow(lev[i] / counts[i], w[i]);
        double mcs = lev[9] / counts[4];   // cs of LAST level
        double output = pow(mcs, w[4]) * prod;
        out[0] = (float)(1.0 - output);
    }
}

// ---------------------------------------------------------------------------
extern "C" void kernel_launch(void* const* d_in, const int* in_sizes, int n_in,
                              void* d_out, int out_size, void* d_ws, size_t ws_size,
                              hipStream_t stream) {
    const float* img1 = (const float*)d_in[0];
    const float* img2 = (const float*)d_in[1];
    float* out = (float*)d_out;

    char* ws = (char*)d_ws;
    float* g = (float*)ws;                         // 11 floats
    float2* partials = (float2*)(ws + 256);        // 16368 float2 = 131 KB
    float* buf = (float*)(ws + 256 + NPART * sizeof(float2));  // pyramid buffers

    const int NC = 48;                      // 16 * 3
    const int Hs[5] = {512, 256, 128, 64, 32};

    const float* A[5]; const float* B[5];
    float* Aw[5]; float* Bw[5];
    A[0] = img1; B[0] = img2;
    Aw[0] = Bw[0] = nullptr;
    size_t o = 0;
    for (int l = 1; l < 5; ++l) {
        size_t n = (size_t)NC * Hs[l] * Hs[l];
        Aw[l] = buf + o; o += n;
        Bw[l] = buf + o; o += n;
        A[l] = Aw[l]; B[l] = Bw[l];
    }

    const int OFF[5] = {0, NB0, NB0 + NB1, NB0 + NB1 + NB2, NB0 + NB1 + NB2 + NB3};

    msssim_init_kernel<<<dim3(1), dim3(64), 0, stream>>>(g);

    for (int l = 0; l < 5; ++l) {
        int H = Hs[l];
        int nt = H / TS;                    // exact for all 5 levels
        dim3 grid(nt, nt, NC);
        float* po1 = (l < 4) ? Aw[l + 1] : nullptr;
        float* po2 = (l < 4) ? Bw[l + 1] : nullptr;
        ssim_fused_kernel<<<grid, dim3(256), 0, stream>>>(
            A[l], B[l], H, g, partials + OFF[l], po1, po2);
    }

    msssim_reduce_kernel<<<dim3(1), dim3(1024), 0, stream>>>(partials, out);
}

// Round 4
// 221.375 us; speedup vs baseline: 2.6196x; 1.0328x over previous
//
#include <hip/hip_runtime.h>
#include <math.h>

#define TS 32      // output tile (TS x TS)
#define HW 42      // halo width = TS + 10
#define SPAD 44    // sAB column stride (float2 pairs) -> 352 B rows, 16B-aligned
#define VPAD 45    // vrt column stride (float4)

// per-level block counts / offsets into the partials buffer (grid = (H/32)^2 * 48)
#define NB0 12288
#define NB1 3072
#define NB2 768
#define NB3 192
#define NB4 48
#define NPART 16368

// ---------------------------------------------------------------------------
// init: 11-tap Gaussian in double (matches numpy f64 -> f32 cast).
// ---------------------------------------------------------------------------
__global__ void msssim_init_kernel(float* __restrict__ g) {
    if (threadIdx.x == 0) {
        double w[11]; double s = 0.0;
        for (int i = 0; i < 11; ++i) { double x = (double)(i - 5); w[i] = exp(-(x * x) / 4.5); s += w[i]; }
        for (int i = 0; i < 11; ++i) g[i] = (float)(w[i] / s);
    }
}

// products per pixel: {a, b, a^2+b^2, a*b}
__device__ __forceinline__ float4 prodf(float2 ab) {
    return make_float4(ab.x, ab.y, fmaf(ab.x, ab.x, ab.y * ab.y), ab.x * ab.y);
}

// 11-tap conv over rotating window w[(I+k)%11], all indices compile-time.
template<int I>
__device__ __forceinline__ float4 conv11(const float4 (&w)[11], const float (&g)[11]) {
    const float4& w0 = w[I % 11];
    float4 r;
    r.x = w0.x * g[0]; r.y = w0.y * g[0]; r.z = w0.z * g[0]; r.w = w0.w * g[0];
#pragma unroll
    for (int k = 1; k < 11; ++k) {
        const float4& wk = w[(I + k) % 11];
        r.x = fmaf(g[k], wk.x, r.x);
        r.y = fmaf(g[k], wk.y, r.y);
        r.z = fmaf(g[k], wk.z, r.z);
        r.w = fmaf(g[k], wk.w, r.w);
    }
    return r;
}

// ---------------------------------------------------------------------------
// Fused per-level kernel, two 16-row halves to halve vrt LDS (26.4 KB total
// -> 6 blocks/CU): stage -> pool -> {vert half, horiz half + formula} x2 ->
// block reduce -> per-block float2 partial store.
// Grid: (H/32, H/32, 48). Block: 256.
// ---------------------------------------------------------------------------
__global__ __launch_bounds__(256, 6) void ssim_fused_kernel(
    const float* __restrict__ img1, const float* __restrict__ img2,
    int H, const float* __restrict__ gg,
    float2* __restrict__ partials,
    float* __restrict__ o1, float* __restrict__ o2)
{
    __shared__ __align__(16) float2 sAB[HW][SPAD];   // {a,b} interleaved, 14784 B
    __shared__ __align__(16) float4 vrt[16][VPAD];   // half-tile vertical results, 11520 B
    __shared__ float gsh[11];
    __shared__ float red[8];

    const int tid = threadIdx.x;
    if (tid < 11) gsh[tid] = gg[tid];

    const int W = H, Hv = H - 10, Wv = W - 10;
    const int bx = blockIdx.x * TS, by = blockIdx.y * TS;
    const size_t plane = (size_t)blockIdx.z * (size_t)H * (size_t)W;
    const float* __restrict__ p1 = img1 + plane;
    const float* __restrict__ p2 = img2 + plane;

    // ---- stage halo tile: pairs of pixels, write {a0,b0,a1,b1} as b128
    for (int i = tid; i < HW * 21; i += 256) {
        int r = i / 21, j = i - r * 21, cc = 2 * j;
        int y = by + r, x = bx + cc;
        float2 a = make_float2(0.f, 0.f), b = a;
        if (y < H && x + 1 < W) {
            size_t o = (size_t)y * W + x;
            a = *(const float2*)(p1 + o);
            b = *(const float2*)(p2 + o);
        }
        *(float4*)&sAB[r][cc] = make_float4(a.x, b.x, a.y, b.y);
    }
    __syncthreads();

    float g[11];
#pragma unroll
    for (int j = 0; j < 11; ++j) g[j] = gsh[j];

    // ---- fused 2x2 avg-pool of this block's owned 32x32 input region
    if (o1) {
        int py = tid >> 4, px = tid & 15;
        float4 q0 = *(const float4*)&sAB[2 * py][2 * px];
        float4 q1 = *(const float4*)&sAB[2 * py + 1][2 * px];
        int Hp = H >> 1;
        size_t po = (size_t)blockIdx.z * Hp * Hp + (size_t)((by >> 1) + py) * Hp + (bx >> 1) + px;
        o1[po] = 0.25f * ((q0.x + q0.z) + (q1.x + q1.z));
        o2[po] = 0.25f * ((q0.y + q0.w) + (q1.y + q1.w));
    }

    // vertical work split: 42 cols x 6 chunks; rows per chunk {3,3,3,3,2,2}
    const int cvert = tid % 42, chv = tid / 42;          // chv 0..6 (tid<252 active)
    const int r0v = (chv < 4) ? 3 * chv : 12 + 2 * (chv - 4);   // {0,3,6,9,12,14}
    const int lenv = (chv < 4) ? 3 : 2;

    const float C1 = 0.0004f;   // (0.01*2)^2
    const float C2 = 0.0036f;   // (0.03*2)^2
    float ssim_l = 0.f, cs_l = 0.f;

#pragma unroll
    for (int p = 0; p < 2; ++p) {
        if (p) __syncthreads();          // vrt overwrite vs previous horiz reads

        // ---- vertical conv for rows [16p, 16p+16)
        if (tid < 252) {
            const int base = 16 * p + r0v;
            float4 w[11];
#pragma unroll
            for (int j = 0; j < 10; ++j) w[j] = prodf(sAB[base + j][cvert]);
#define P1STEP(I)                                                      \
            if ((I) < 2 || lenv == 3) {                                \
                w[(10 + (I)) % 11] = prodf(sAB[base + 10 + (I)][cvert]); \
                vrt[r0v + (I)][cvert] = conv11<(I)>(w, g);             \
            }
            P1STEP(0) P1STEP(1) P1STEP(2)
#undef P1STEP
        }
        __syncthreads();

        // ---- horizontal conv + SSIM formula: 16 rows x 16 threads x 2 cols
        {
            const int row = tid >> 4, c0 = (tid & 15) * 2;
            const int oy = by + 16 * p + row;
            float4 w[11];
#pragma unroll
            for (int j = 0; j < 10; ++j) w[j] = vrt[row][c0 + j];
#define P2STEP(I)                                                      \
            {                                                          \
                w[(10 + (I)) % 11] = vrt[row][c0 + 10 + (I)];          \
                float4 m = conv11<(I)>(w, g);                          \
                int ox = bx + c0 + (I);                                \
                if (oy < Hv && ox < Wv) {                              \
                    float ab   = m.x * m.y;                            \
                    float aabb = fmaf(m.x, m.x, m.y * m.y);            \
                    float n1   = fmaf(2.f, ab, C1);                    \
                    float d1   = aabb + C1;                            \
                    float v1   = fmaf(2.f, m.w - ab, C2);              \
                    float v2   = (m.z - aabb) + C2;                    \
                    float rden = 1.f / (d1 * v2);                      \
                    cs_l   = fmaf(v1 * d1, rden, cs_l);                \
                    ssim_l = fmaf(n1 * v1, rden, ssim_l);              \
                }                                                      \
            }
            P2STEP(0) P2STEP(1)
#undef P2STEP
        }
    }

    // ---- block reduction (4 waves of 64) -> one float2 store per block
#pragma unroll
    for (int off = 32; off > 0; off >>= 1) {
        ssim_l += __shfl_down(ssim_l, off);
        cs_l   += __shfl_down(cs_l, off);
    }
    int wave = tid >> 6, lane = tid & 63;
    if (lane == 0) { red[wave] = ssim_l; red[4 + wave] = cs_l; }
    __syncthreads();
    if (tid == 0) {
        float ss = red[0] + red[1] + red[2] + red[3];
        float cc = red[4] + red[5] + red[6] + red[7];
        int nt = gridDim.x;
        int bid = ((int)blockIdx.z * nt + (int)blockIdx.y) * nt + (int)blockIdx.x;
        partials[bid] = make_float2(ss, cc);
    }
}

// ---------------------------------------------------------------------------
// Final reduce: sum per-level partials in double, then
// loss = 1 - cs4^w4 * prod_i ssim_i^w_i   (all in double). One block, 1024 thr.
// ---------------------------------------------------------------------------
__global__ __launch_bounds__(1024) void msssim_reduce_kernel(
    const float2* __restrict__ partials, float* __restrict__ out)
{
    __shared__ double sred[16][2];
    __shared__ double lev[10];
    const int NB[5]  = {NB0, NB1, NB2, NB3, NB4};
    const int OFF[5] = {0, NB0, NB0 + NB1, NB0 + NB1 + NB2, NB0 + NB1 + NB2 + NB3};
    const int tid = threadIdx.x;
    const int wv = tid >> 6, ln = tid & 63;

    for (int l = 0; l < 5; ++l) {
        double s = 0.0, c = 0.0;
        for (int i = tid; i < NB[l]; i += 1024) {
            float2 p = partials[OFF[l] + i];
            s += (double)p.x; c += (double)p.y;
        }
#pragma unroll
        for (int off = 32; off > 0; off >>= 1) {
            s += __shfl_down(s, off);
            c += __shfl_down(c, off);
        }
        if (ln == 0) { sred[wv][0] = s; sred[wv][1] = c; }
        __syncthreads();
        if (tid == 0) {
            double ss = 0.0, cc = 0.0;
            for (int w = 0; w < 16; ++w) { ss += sred[w][0]; cc += sred[w][1]; }
            lev[l] = ss; lev[5 + l] = cc;
        }
        __syncthreads();
    }

    if (tid == 0) {
        const double counts[5] = {
            48.0 * 502.0 * 502.0,
            48.0 * 246.0 * 246.0,
            48.0 * 118.0 * 118.0,
            48.0 * 54.0 * 54.0,
            48.0 * 22.0 * 22.0
        };
        const double w[5] = { (double)0.0448f, (double)0.2856f, (double)0.3001f,
                              (double)0.2363f, (double)0.1333f };
        double prod = 1.0;
        for (int i = 0; i < 5; ++i) prod *= pow(lev[i] / counts[i], w[i]);
        double mcs = lev[9] / counts[4];   // cs of LAST level
        double output = pow(mcs, w[4]) * prod;
        out[0] = (float)(1.0 - output);
    }
}

// ---------------------------------------------------------------------------
extern "C" void kernel_launch(void* const* d_in, const int* in_sizes, int n_in,
                              void* d_out, int out_size, void* d_ws, size_t ws_size,
                              hipStream_t stream) {
    const float* img1 = (const float*)d_in[0];
    const float* img2 = (const float*)d_in[1];
    float* out = (float*)d_out;

    char* ws = (char*)d_ws;
    float* g = (float*)ws;                         // 11 floats
    float2* partials = (float2*)(ws + 256);        // 16368 float2 = 131 KB
    float* buf = (float*)(ws + 256 + NPART * sizeof(float2));  // pyramid buffers

    const int NC = 48;                      // 16 * 3
    const int Hs[5] = {512, 256, 128, 64, 32};

    const float* A[5]; const float* B[5];
    float* Aw[5]; float* Bw[5];
    A[0] = img1; B[0] = img2;
    Aw[0] = Bw[0] = nullptr;
    size_t o = 0;
    for (int l = 1; l < 5; ++l) {
        size_t n = (size_t)NC * Hs[l] * Hs[l];
        Aw[l] = buf + o; o += n;
        Bw[l] = buf + o; o += n;
        A[l] = Aw[l]; B[l] = Bw[l];
    }

    const int OFF[5] = {0, NB0, NB0 + NB1, NB0 + NB1 + NB2, NB0 + NB1 + NB2 + NB3};

    msssim_init_kernel<<<dim3(1), dim3(64), 0, stream>>>(g);

    for (int l = 0; l < 5; ++l) {
        int H = Hs[l];
        int nt = H / TS;                    // exact for all 5 levels
        dim3 grid(nt, nt, NC);
        float* po1 = (l < 4) ? Aw[l + 1] : nullptr;
        float* po2 = (l < 4) ? Bw[l + 1] : nullptr;
        ssim_fused_kernel<<<grid, dim3(256), 0, stream>>>(
            A[l], B[l], H, g, partials + OFF[l], po1, po2);
    }

    msssim_reduce_kernel<<<dim3(1), dim3(1024), 0, stream>>>(partials, out);
}